// Round 12
// baseline (1213.467 us; speedup 1.0000x reference)
//
#include <hip/hip_runtime.h>
#include <math.h>

// B=32, Cin=64, H=W=56, Cout=128, K=3 pad=1 -> D=576, out (32,128,56,56) fp32
#define B_    32
#define CIN   64
#define HH    56
#define WW    56
#define COUT  128
#define DD    576
#define KC    384            // OpenBLAS kc split (verified R9)
#define TOTAL (B_*COUT*HH*WW)

#define CCH    4             // channels per LDS W-chunk
#define TROWS  14            // output rows per block tile
#define MARGIN 2e-4f         // |z - boundary| < this -> exact replay (bound 3.5e-5)

// ---- bit-exact numpy FLOAT_sin (npyv FMA path) — verified R9 ----
__device__ __forceinline__ float np_sinf(float x) {
#pragma clang fp contract(off)
    const float rint_cvt = 0x1.8p+23f;
    float q = __fmul_rn(x, 0x1.45f306p-1f);
    q = __fadd_rn(q, rint_cvt);
    q = __fsub_rn(q, rint_cvt);
    float r = fmaf(q, -0x1.921fb0p+0f, x);
    r = fmaf(q, -0x1.5110b4p-22f, r);
    r = fmaf(q, -0x1.846988p-48f, r);
    float r2 = __fmul_rn(r, r);
    float s = fmaf(0x1.7d3bbcp-19f, r2, -0x1.a06bbap-13f);
    s = fmaf(s, r2, 0x1.11119ap-7f);
    s = fmaf(s, r2, -0x1.555556p-3f);
    s = __fmul_rn(s, r2);
    s = fmaf(s, r, r);
    float c = fmaf(0x1.98e616p-16f, r2, -0x1.6c06dcp-10f);
    c = fmaf(c, r2, 0x1.55553cp-5f);
    c = fmaf(c, r2, -0.5f);
    c = fmaf(c, r2, 1.0f);
    int iq = (int)q;
    float res = (iq & 1) ? c : s;
    unsigned sgn = ((unsigned)(iq & 2)) << 30;
    return __uint_as_float(__float_as_uint(res) ^ sgn);
}

__device__ __forceinline__ int dec_np(float z) {
    float s = np_sinf(z);
    return (__fmul_rn(s, s) > 0.5f) ? 1 : 0;
}

// ---- W transpose (+ worklist counter zero): W[128][576] -> WT[576][128] ----
__global__ __launch_bounds__(256)
void transpose_w(const float* __restrict__ W, float* __restrict__ WT,
                 unsigned* __restrict__ wcount) {
    if (blockIdx.x == 0 && blockIdx.y == 0 && threadIdx.x == 0) *wcount = 0;
    __shared__ float t[32][33];
    int d0 = blockIdx.x * 32, o0 = blockIdx.y * 32;
    int tx = threadIdx.x & 31, ty = threadIdx.x >> 5;   // ty 0..7
    for (int r = ty; r < 32; r += 8)
        t[r][tx] = W[(size_t)(o0 + r) * DD + d0 + tx];
    __syncthreads();
    for (int r = ty; r < 32; r += 8)
        WT[(size_t)(d0 + r) * COUT + o0 + tx] = t[tx][r];
}

// ---- fast conv: 128 o x (14 rows x 8 cols); thread = 8o x 8px ----
// W staged in LDS (broadcast reads); x read DIRECT from global (VMEM pipe,
// L1/L2 reuse) — removes the LDS-bandwidth bottleneck measured in R11.
// Decision: sin^2(z)>0.5 <=> round(z*2/pi) odd; borderline -> worklist.
__global__ __launch_bounds__(256)
void fast_conv(const float* __restrict__ x,
               const float* __restrict__ WT,
               const float* __restrict__ bias,
               float* __restrict__ out,
               unsigned* __restrict__ wcount,
               unsigned* __restrict__ wlist,
               unsigned wcap) {
    __shared__ __align__(16) float sW[CCH * 9 * COUT];   // 18432 B

    const int tid = threadIdx.x;
    const int x0  = blockIdx.x * 8;      // 0,8,...,48
    const int y0  = blockIdx.y * TROWS;  // 0,14,28,42
    const int b   = blockIdx.z;

    const int og = tid >> 4;             // 0..15
    const int pg = tid & 15;             // 0..15
    const int ry = (pg < TROWS) ? pg : (TROWS - 1);
    const bool active = (pg < TROWS);
    const int obase = og * 8;

    float acc[8][8];
#pragma unroll
    for (int j = 0; j < 8; ++j)
#pragma unroll
        for (int i = 0; i < 8; ++i) acc[j][i] = 0.f;

    const float4 f4z = make_float4(0.f, 0.f, 0.f, 0.f);

    for (int c0 = 0; c0 < CIN; c0 += CCH) {
        __syncthreads();
        // stage W chunk: 36 rows x 128 o = 1152 float4, coalesced, linear LDS
        {
            const float4* gsrc = (const float4*)(WT + (size_t)c0 * 9 * COUT);
            float4* ldst = (float4*)sW;
#pragma unroll
            for (int r = 0; r < 4; ++r)
                ldst[tid + r * 256] = gsrc[tid + r * 256];
            if (tid < 128) ldst[tid + 1024] = gsrc[tid + 1024];
        }
        __syncthreads();
#pragma unroll
        for (int cc = 0; cc < CCH; ++cc) {
            const float* xrow0 =
                x + ((size_t)((b * CIN + c0 + cc) * HH) + (y0 + ry - 1)) * WW;
#pragma unroll
            for (int u = 0; u < 3; ++u) {
                const int gy = y0 + ry + u - 1;
                const bool vy = (unsigned)gy < HH;
                const float* xr = xrow0 + u * WW;
                float xv[10];
                if (x0 == 0) {                     // block-uniform branch
                    float4 a  = vy ? *(const float4*)(xr + 0) : f4z;
                    float4 bq = vy ? *(const float4*)(xr + 4) : f4z;
                    float  c8 = vy ? xr[8] : 0.f;
                    xv[0] = 0.f;  xv[1] = a.x;  xv[2] = a.y;  xv[3] = a.z;
                    xv[4] = a.w;  xv[5] = bq.x; xv[6] = bq.y; xv[7] = bq.z;
                    xv[8] = bq.w; xv[9] = c8;
                } else if (x0 == 48) {
                    float4 a  = vy ? *(const float4*)(xr + 47) : f4z;
                    float4 bq = vy ? *(const float4*)(xr + 51) : f4z;
                    float  c8 = vy ? xr[55] : 0.f;
                    xv[0] = a.x;  xv[1] = a.y;  xv[2] = a.z;  xv[3] = a.w;
                    xv[4] = bq.x; xv[5] = bq.y; xv[6] = bq.z; xv[7] = bq.w;
                    xv[8] = c8;   xv[9] = 0.f;
                } else {
                    float4 a  = vy ? *(const float4*)(xr + x0 - 1) : f4z;
                    float4 bq = vy ? *(const float4*)(xr + x0 + 3) : f4z;
                    float2 c2 = vy ? *(const float2*)(xr + x0 + 7)
                                   : make_float2(0.f, 0.f);
                    xv[0] = a.x;  xv[1] = a.y;  xv[2] = a.z;  xv[3] = a.w;
                    xv[4] = bq.x; xv[5] = bq.y; xv[6] = bq.z; xv[7] = bq.w;
                    xv[8] = c2.x; xv[9] = c2.y;
                }
#pragma unroll
                for (int v = 0; v < 3; ++v) {
                    const float* wr = &sW[(cc * 9 + u * 3 + v) * COUT + obase];
                    float4 wA = *(const float4*)(wr);
                    float4 wB = *(const float4*)(wr + 4);
                    float wv[8] = {wA.x, wA.y, wA.z, wA.w,
                                   wB.x, wB.y, wB.z, wB.w};
#pragma unroll
                    for (int j = 0; j < 8; ++j)
#pragma unroll
                        for (int i = 0; i < 8; ++i)
                            acc[j][i] = fmaf(wv[j], xv[i + v], acc[j][i]);
                }
            }
        }
    }

    if (!active) return;
    const int py = y0 + ry;
#pragma unroll
    for (int j = 0; j < 8; ++j) {
        const int o = obase + j;
        const float bz = bias[o];
        const size_t rowoff = ((size_t)(b * COUT + o) * HH + py) * WW + x0;
        float res[8];
#pragma unroll
        for (int i = 0; i < 8; ++i) {
            float z = acc[j][i] + bz;
            float q = rintf(__fmul_rn(z, 0.63661975f));    // round(z*2/pi)
            float r = fmaf(q, -1.5707964f, z);             // z - q*pi/2
            res[i] = (float)(((int)q) & 1);                // parity decision
            float d = fabsf(fabsf(r) - 0.78539816f);       // dist to boundary
            if (d < MARGIN) {                              // ~3e-4 of elements
                unsigned pos = atomicAdd(wcount, 1u);
                if (pos < wcap) wlist[pos] = (unsigned)(rowoff + i);
            }
        }
        *(float4*)(out + rowoff)     = make_float4(res[0], res[1], res[2], res[3]);
        *(float4*)(out + rowoff + 4) = make_float4(res[4], res[5], res[6], res[7]);
    }
}

// ---- exact replay of the verified R9 reference emulation (bit-exact) ----
__global__ __launch_bounds__(256)
void exact_fix(const float* __restrict__ x,
               const float* __restrict__ Wt,
               const float* __restrict__ bias,
               float* __restrict__ out,
               const unsigned* __restrict__ wcount,
               const unsigned* __restrict__ wlist,
               unsigned wcap) {
#pragma clang fp contract(off)
    unsigned n = *wcount;
    if (n > wcap) n = wcap;
    for (unsigned k = blockIdx.x * 256 + threadIdx.x; k < n; k += gridDim.x * 256) {
        unsigned idx = wlist[k];
        int px = idx % WW;
        unsigned t = idx / WW;
        int py = t % HH;  t /= HH;
        int o  = t % COUT;
        int b  = t / COUT;

        const float* wrow = Wt + (size_t)o * DD;
        const float* xb   = x + (size_t)b * CIN * HH * WW;

        int  voff[9];
        bool vok[9];
#pragma unroll
        for (int u = 0; u < 3; ++u)
#pragma unroll
            for (int v = 0; v < 3; ++v) {
                int gy = py + u - 1, gx = px + v - 1;
                vok[u * 3 + v]  = ((unsigned)gy < HH) && ((unsigned)gx < WW);
                voff[u * 3 + v] = gy * WW + gx;
            }

        float accA = 0.f, accB2 = 0.f;    // kc=384-split sequential FMA chains
        for (int c = 0; c < CIN; ++c) {
            const float* xc = xb + c * (HH * WW);
            const float* wc = wrow + c * 9;
            int dbase = c * 9;
#pragma unroll
            for (int tp = 0; tp < 9; ++tp) {
                float p = vok[tp] ? xc[voff[tp]] : 0.f;
                float w = wc[tp];
                if (dbase + tp < KC) accA  = fmaf(p, w, accA);
                else                 accB2 = fmaf(p, w, accB2);
            }
        }
        float zG = __fadd_rn(accA, accB2);
        float z  = __fadd_rn(zG, bias[o]);
        out[idx] = (float)dec_np(z);
    }
}

// ---- fallback (verified R9 path) if workspace is unexpectedly tiny ----
__global__ __launch_bounds__(256)
void np_emul_conv(const float* __restrict__ x,
                  const float* __restrict__ Wt,
                  const float* __restrict__ bias,
                  float* __restrict__ out) {
#pragma clang fp contract(off)
    int idx = blockIdx.x * 256 + threadIdx.x;
    if (idx >= TOTAL) return;
    int px = idx % WW;
    int t  = idx / WW;
    int py = t % HH;  t /= HH;
    int o  = t % COUT;
    int b  = t / COUT;
    const float* wrow = Wt + (size_t)o * DD;
    const float* xb   = x + (size_t)b * CIN * HH * WW;
    float accA = 0.f, accB2 = 0.f;
    for (int c = 0; c < CIN; ++c) {
        const float* xc = xb + c * (HH * WW);
        const float* wc = wrow + c * 9;
        int dbase = c * 9;
#pragma unroll
        for (int u = 0; u < 3; ++u)
#pragma unroll
            for (int v = 0; v < 3; ++v) {
                int tp = u * 3 + v;
                int gy = py + u - 1, gx = px + v - 1;
                float p = ((unsigned)gy < HH && (unsigned)gx < WW) ? xc[gy * WW + gx] : 0.f;
                if (dbase + tp < KC) accA  = fmaf(p, wc[tp], accA);
                else                 accB2 = fmaf(p, wc[tp], accB2);
            }
    }
    float z = __fadd_rn(__fadd_rn(accA, accB2), bias[o]);
    out[idx] = (float)dec_np(z);
}

extern "C" void kernel_launch(void* const* d_in, const int* in_sizes, int n_in,
                              void* d_out, int out_size, void* d_ws, size_t ws_size,
                              hipStream_t stream) {
    const float* x  = (const float*)d_in[0];
    const float* Wt = (const float*)d_in[1];
    const float* bb = (const float*)d_in[2];
    float* out = (float*)d_out;

    const size_t WT_BYTES = (size_t)DD * COUT * 4;   // 294912
    if (ws_size < WT_BYTES + 4 + 65536) {            // fallback: verified R9 path
        np_emul_conv<<<(TOTAL + 255) / 256, 256, 0, stream>>>(x, Wt, bb, out);
        return;
    }

    float*    WTd    = (float*)d_ws;
    unsigned* wcount = (unsigned*)((char*)d_ws + WT_BYTES);
    unsigned* wlist  = wcount + 1;
    size_t avail = (ws_size - WT_BYTES - 4) / 4;
    unsigned wcap = (avail > 2000000u) ? 2000000u : (unsigned)avail;

    transpose_w<<<dim3(DD / 32, COUT / 32), dim3(256), 0, stream>>>(Wt, WTd, wcount);
    fast_conv<<<dim3(7, 4, B_), dim3(256), 0, stream>>>(x, WTd, bb, out,
                                                        wcount, wlist, wcap);
    exact_fix<<<dim3(64), dim3(256), 0, stream>>>(x, Wt, bb, out,
                                                  wcount, wlist, wcap);
}

// Round 13
// 531.371 us; speedup vs baseline: 2.2837x; 2.2837x over previous
//
#include <hip/hip_runtime.h>
#include <math.h>

// B=32, Cin=64, H=W=56, Cout=128, K=3 pad=1 -> D=576, out (32,128,56,56) fp32
#define B_    32
#define CIN   64
#define HH    56
#define WW    56
#define COUT  128
#define DD    576
#define KC    384            // OpenBLAS kc split (verified R9)
#define TOTAL (B_*COUT*HH*WW)

#define CCH    4             // channels per LDS chunk
#define XSTR   12            // sX row stride (10 padded to 12, 16B-aligned)
#define HR     18            // halo rows per chunk (16 tile rows + 2)
#define MARGIN 2e-4f         // |z - boundary| < this -> exact replay (bound 3.5e-5)

// ---- bit-exact numpy FLOAT_sin (npyv FMA path) — verified R9 ----
__device__ __forceinline__ float np_sinf(float x) {
#pragma clang fp contract(off)
    const float rint_cvt = 0x1.8p+23f;
    float q = __fmul_rn(x, 0x1.45f306p-1f);
    q = __fadd_rn(q, rint_cvt);
    q = __fsub_rn(q, rint_cvt);
    float r = fmaf(q, -0x1.921fb0p+0f, x);
    r = fmaf(q, -0x1.5110b4p-22f, r);
    r = fmaf(q, -0x1.846988p-48f, r);
    float r2 = __fmul_rn(r, r);
    float s = fmaf(0x1.7d3bbcp-19f, r2, -0x1.a06bbap-13f);
    s = fmaf(s, r2, 0x1.11119ap-7f);
    s = fmaf(s, r2, -0x1.555556p-3f);
    s = __fmul_rn(s, r2);
    s = fmaf(s, r, r);
    float c = fmaf(0x1.98e616p-16f, r2, -0x1.6c06dcp-10f);
    c = fmaf(c, r2, 0x1.55553cp-5f);
    c = fmaf(c, r2, -0.5f);
    c = fmaf(c, r2, 1.0f);
    int iq = (int)q;
    float res = (iq & 1) ? c : s;
    unsigned sgn = ((unsigned)(iq & 2)) << 30;
    return __uint_as_float(__float_as_uint(res) ^ sgn);
}

__device__ __forceinline__ int dec_np(float z) {
    float s = np_sinf(z);
    return (__fmul_rn(s, s) > 0.5f) ? 1 : 0;
}

// ---- W transpose (+ worklist counter zero): W[128][576] -> WT[576][128] ----
__global__ __launch_bounds__(256)
void transpose_w(const float* __restrict__ W, float* __restrict__ WT,
                 unsigned* __restrict__ wcount) {
    if (blockIdx.x == 0 && blockIdx.y == 0 && threadIdx.x == 0) *wcount = 0;
    __shared__ float t[32][33];
    int d0 = blockIdx.x * 32, o0 = blockIdx.y * 32;
    int tx = threadIdx.x & 31, ty = threadIdx.x >> 5;
    for (int r = ty; r < 32; r += 8)
        t[r][tx] = W[(size_t)(o0 + r) * DD + d0 + tx];
    __syncthreads();
    for (int r = ty; r < 32; r += 8)
        WT[(size_t)(d0 + r) * COUT + o0 + tx] = t[tx][r];
}

// ---- fast conv: block = 128 o x (16 rows x 8 cols); thread = 4o x (2x8)px ----
// All-LDS data path (R12 global-x falsified: VGPR 248, occupancy 10%).
// Work-shape 4o x 16px halves W LDS traffic/FMA vs R11 -> LDS demand ~79%.
__global__ __launch_bounds__(256)
void fast_conv(const float* __restrict__ x,
               const float* __restrict__ WT,
               const float* __restrict__ bias,
               float* __restrict__ out,
               unsigned* __restrict__ wcount,
               unsigned* __restrict__ wlist,
               unsigned wcap) {
    __shared__ __align__(16) float sW[CCH * 9 * COUT];   // 18432 B
    __shared__ __align__(16) float sX[CCH * HR * XSTR];  // 3456 B

    const int tid = threadIdx.x;
    const int x0  = blockIdx.x * 8;      // 0..48
    const int y0  = blockIdx.y * 16;     // 0,16,32,48 (48-tile: rows>=56 masked)
    const int b   = blockIdx.z;

    const int og = tid >> 3;             // 0..31 -> o block of 4
    const int pg = tid & 7;              // 0..7  -> row pair
    const int obase = og * 4;
    const int r0 = pg * 2;               // first tile-row of the pair

    float acc[4][16];                    // [o][row*8+col]
#pragma unroll
    for (int j = 0; j < 4; ++j)
#pragma unroll
        for (int i = 0; i < 16; ++i) acc[j][i] = 0.f;

    for (int c0 = 0; c0 < CIN; c0 += CCH) {
        __syncthreads();
        // stage W chunk: 36 rows x 128 o = 1152 float4, coalesced, linear LDS
        {
            const float4* gsrc = (const float4*)(WT + (size_t)c0 * 9 * COUT);
            float4* ldst = (float4*)sW;
#pragma unroll
            for (int r = 0; r < 4; ++r)
                ldst[tid + r * 256] = gsrc[tid + r * 256];
            if (tid < 128) ldst[tid + 1024] = gsrc[tid + 1024];
        }
        // stage x chunk: 4 cc x 18 halo rows x 10 cols (stride 12)
        for (int t = tid; t < CCH * HR * 10; t += 256) {
            int cc  = t / (HR * 10);
            int rem = t - cc * (HR * 10);
            int h   = rem / 10;
            int s   = rem - h * 10;
            int gy = y0 + h - 1, gx = x0 + s - 1;
            float v = 0.f;
            if ((unsigned)gy < HH && (unsigned)gx < WW)
                v = x[((size_t)(b * CIN + c0 + cc) * HH + gy) * WW + gx];
            sX[cc * (HR * XSTR) + h * XSTR + s] = v;
        }
        __syncthreads();
#pragma unroll
        for (int cc = 0; cc < CCH; ++cc) {
            // 4 halo rows r0..r0+3 (10 wide) into registers
            float xr[4][10];
#pragma unroll
            for (int t = 0; t < 4; ++t) {
                const float* p = &sX[cc * (HR * XSTR) + (r0 + t) * XSTR];
                float4 a  = *(const float4*)(p);
                float4 bq = *(const float4*)(p + 4);
                float2 c2 = *(const float2*)(p + 8);
                xr[t][0] = a.x;  xr[t][1] = a.y;  xr[t][2] = a.z;  xr[t][3] = a.w;
                xr[t][4] = bq.x; xr[t][5] = bq.y; xr[t][6] = bq.z; xr[t][7] = bq.w;
                xr[t][8] = c2.x; xr[t][9] = c2.y;
            }
#pragma unroll
            for (int u = 0; u < 3; ++u)
#pragma unroll
                for (int v = 0; v < 3; ++v) {
                    float4 w4 = *(const float4*)&sW[(cc * 9 + u * 3 + v) * COUT + obase];
                    float wv[4] = {w4.x, w4.y, w4.z, w4.w};
#pragma unroll
                    for (int j = 0; j < 4; ++j)
#pragma unroll
                        for (int r = 0; r < 2; ++r)
#pragma unroll
                            for (int i = 0; i < 8; ++i)
                                acc[j][r * 8 + i] =
                                    fmaf(wv[j], xr[u + r][v + i], acc[j][r * 8 + i]);
                }
        }
    }

#pragma unroll
    for (int j = 0; j < 4; ++j) {
        const int o = obase + j;
        const float bz = bias[o];
#pragma unroll
        for (int r = 0; r < 2; ++r) {
            const int py = y0 + r0 + r;
            if (py >= HH) continue;                       // mask y3 overhang
            const size_t rowoff = ((size_t)(b * COUT + o) * HH + py) * WW + x0;
            float res[8];
#pragma unroll
            for (int i = 0; i < 8; ++i) {
                float z = acc[j][r * 8 + i] + bz;
                float q = rintf(__fmul_rn(z, 0.63661975f));   // round(z*2/pi)
                float rr = fmaf(q, -1.5707964f, z);           // z - q*pi/2
                res[i] = (float)(((int)q) & 1);               // parity decision
                float d = fabsf(fabsf(rr) - 0.78539816f);     // dist to boundary
                if (d < MARGIN) {                             // ~2.5e-4 of elems
                    unsigned pos = atomicAdd(wcount, 1u);
                    if (pos < wcap) wlist[pos] = (unsigned)(rowoff + i);
                }
            }
            *(float4*)(out + rowoff)     = make_float4(res[0], res[1], res[2], res[3]);
            *(float4*)(out + rowoff + 4) = make_float4(res[4], res[5], res[6], res[7]);
        }
    }
}

// ---- exact replay of the verified R9 reference emulation (bit-exact) ----
__global__ __launch_bounds__(256)
void exact_fix(const float* __restrict__ x,
               const float* __restrict__ Wt,
               const float* __restrict__ bias,
               float* __restrict__ out,
               const unsigned* __restrict__ wcount,
               const unsigned* __restrict__ wlist,
               unsigned wcap) {
#pragma clang fp contract(off)
    unsigned n = *wcount;
    if (n > wcap) n = wcap;
    for (unsigned k = blockIdx.x * 256 + threadIdx.x; k < n; k += gridDim.x * 256) {
        unsigned idx = wlist[k];
        int px = idx % WW;
        unsigned t = idx / WW;
        int py = t % HH;  t /= HH;
        int o  = t % COUT;
        int b  = t / COUT;

        const float* wrow = Wt + (size_t)o * DD;
        const float* xb   = x + (size_t)b * CIN * HH * WW;

        int  voff[9];
        bool vok[9];
#pragma unroll
        for (int u = 0; u < 3; ++u)
#pragma unroll
            for (int v = 0; v < 3; ++v) {
                int gy = py + u - 1, gx = px + v - 1;
                vok[u * 3 + v]  = ((unsigned)gy < HH) && ((unsigned)gx < WW);
                voff[u * 3 + v] = gy * WW + gx;
            }

        float accA = 0.f, accB2 = 0.f;    // kc=384-split sequential FMA chains
        for (int c = 0; c < CIN; ++c) {
            const float* xc = xb + c * (HH * WW);
            const float* wc = wrow + c * 9;
            int dbase = c * 9;
#pragma unroll
            for (int tp = 0; tp < 9; ++tp) {
                float p = vok[tp] ? xc[voff[tp]] : 0.f;
                float w = wc[tp];
                if (dbase + tp < KC) accA  = fmaf(p, w, accA);
                else                 accB2 = fmaf(p, w, accB2);
            }
        }
        float zG = __fadd_rn(accA, accB2);
        float z  = __fadd_rn(zG, bias[o]);
        out[idx] = (float)dec_np(z);
    }
}

// ---- fallback (verified R9 path) if workspace is unexpectedly tiny ----
__global__ __launch_bounds__(256)
void np_emul_conv(const float* __restrict__ x,
                  const float* __restrict__ Wt,
                  const float* __restrict__ bias,
                  float* __restrict__ out) {
#pragma clang fp contract(off)
    int idx = blockIdx.x * 256 + threadIdx.x;
    if (idx >= TOTAL) return;
    int px = idx % WW;
    int t  = idx / WW;
    int py = t % HH;  t /= HH;
    int o  = t % COUT;
    int b  = t / COUT;
    const float* wrow = Wt + (size_t)o * DD;
    const float* xb   = x + (size_t)b * CIN * HH * WW;
    float accA = 0.f, accB2 = 0.f;
    for (int c = 0; c < CIN; ++c) {
        const float* xc = xb + c * (HH * WW);
        const float* wc = wrow + c * 9;
        int dbase = c * 9;
#pragma unroll
        for (int u = 0; u < 3; ++u)
#pragma unroll
            for (int v = 0; v < 3; ++v) {
                int tp = u * 3 + v;
                int gy = py + u - 1, gx = px + v - 1;
                float p = ((unsigned)gy < HH && (unsigned)gx < WW) ? xc[gy * WW + gx] : 0.f;
                if (dbase + tp < KC) accA  = fmaf(p, wc[tp], accA);
                else                 accB2 = fmaf(p, wc[tp], accB2);
            }
    }
    float z = __fadd_rn(__fadd_rn(accA, accB2), bias[o]);
    out[idx] = (float)dec_np(z);
}

extern "C" void kernel_launch(void* const* d_in, const int* in_sizes, int n_in,
                              void* d_out, int out_size, void* d_ws, size_t ws_size,
                              hipStream_t stream) {
    const float* x  = (const float*)d_in[0];
    const float* Wt = (const float*)d_in[1];
    const float* bb = (const float*)d_in[2];
    float* out = (float*)d_out;

    const size_t WT_BYTES = (size_t)DD * COUT * 4;   // 294912
    if (ws_size < WT_BYTES + 4 + 65536) {            // fallback: verified R9 path
        np_emul_conv<<<(TOTAL + 255) / 256, 256, 0, stream>>>(x, Wt, bb, out);
        return;
    }

    float*    WTd    = (float*)d_ws;
    unsigned* wcount = (unsigned*)((char*)d_ws + WT_BYTES);
    unsigned* wlist  = wcount + 1;
    size_t avail = (ws_size - WT_BYTES - 4) / 4;
    unsigned wcap = (avail > 2000000u) ? 2000000u : (unsigned)avail;

    transpose_w<<<dim3(DD / 32, COUT / 32), dim3(256), 0, stream>>>(Wt, WTd, wcount);
    fast_conv<<<dim3(7, 4, B_), dim3(256), 0, stream>>>(x, WTd, bb, out,
                                                        wcount, wlist, wcap);
    exact_fix<<<dim3(64), dim3(256), 0, stream>>>(x, Wt, bb, out,
                                                  wcount, wlist, wcap);
}

// Round 14
// 410.227 us; speedup vs baseline: 2.9580x; 1.2953x over previous
//
#include <hip/hip_runtime.h>
#include <math.h>

// B=32, Cin=64, H=W=56, Cout=128, K=3 pad=1 -> D=576, out (32,128,56,56) fp32
#define B_    32
#define CIN   64
#define HH    56
#define WW    56
#define COUT  128
#define DD    576
#define KC    384            // OpenBLAS kc split (verified R9)
#define TOTAL (B_*COUT*HH*WW)

#define CCH    4             // channels per LDS chunk (36 d-rows)
#define XSTR   12            // sX row stride (10 padded to 12)
#define HR     10            // halo rows per chunk (8 tile rows + 2)
#define MARGIN 2e-4f         // |z - boundary| < this -> exact replay (bound 3.5e-5)
#define SENT   2.0f          // sentinel marking borderline elements in out

// ---- bit-exact numpy FLOAT_sin (npyv FMA path) — verified R9 ----
__device__ __forceinline__ float np_sinf(float x) {
#pragma clang fp contract(off)
    const float rint_cvt = 0x1.8p+23f;
    float q = __fmul_rn(x, 0x1.45f306p-1f);
    q = __fadd_rn(q, rint_cvt);
    q = __fsub_rn(q, rint_cvt);
    float r = fmaf(q, -0x1.921fb0p+0f, x);
    r = fmaf(q, -0x1.5110b4p-22f, r);
    r = fmaf(q, -0x1.846988p-48f, r);
    float r2 = __fmul_rn(r, r);
    float s = fmaf(0x1.7d3bbcp-19f, r2, -0x1.a06bbap-13f);
    s = fmaf(s, r2, 0x1.11119ap-7f);
    s = fmaf(s, r2, -0x1.555556p-3f);
    s = __fmul_rn(s, r2);
    s = fmaf(s, r, r);
    float c = fmaf(0x1.98e616p-16f, r2, -0x1.6c06dcp-10f);
    c = fmaf(c, r2, 0x1.55553cp-5f);
    c = fmaf(c, r2, -0.5f);
    c = fmaf(c, r2, 1.0f);
    int iq = (int)q;
    float res = (iq & 1) ? c : s;
    unsigned sgn = ((unsigned)(iq & 2)) << 30;
    return __uint_as_float(__float_as_uint(res) ^ sgn);
}

__device__ __forceinline__ int dec_np(float z) {
    float s = np_sinf(z);
    return (__fmul_rn(s, s) > 0.5f) ? 1 : 0;
}

// ---- fast conv: SINGLE-WAVE blocks (64 thr). Block = 64 o x 8 rows x 8 cols.
// Thread = 4 o x (2 rows x 8 cols). Grid (7,7,64): no masked rows, 3136 blocks
// (12.25/CU) for dispatch balance; barriers degenerate to waitcnt (1 wave).
// W transposed on the fly into LDS (kills the transpose_w dispatch).
// Borderline elements written as sentinel 2.0 (kills worklist/atomics/memset).
__global__ __launch_bounds__(64, 3)
void fast_conv(const float* __restrict__ x,
               const float* __restrict__ W,
               const float* __restrict__ bias,
               float* __restrict__ out) {
    __shared__ __align__(16) float sW[36 * 64];      // [d-row][o'] 9216 B
    __shared__ __align__(16) float sX[CCH * HR * XSTR];  // 1920 B

    const int lane = threadIdx.x;        // 0..63
    const int x0 = blockIdx.x * 8;       // 0..48
    const int y0 = blockIdx.y * 8;       // 0..48 (7*8=56 exact)
    const int bz = blockIdx.z;           // 0..63
    const int b      = bz >> 1;
    const int obase0 = (bz & 1) * 64;

    const int og = lane >> 2;            // 0..15 -> o sub-block of 4
    const int pg = lane & 3;             // 0..3  -> row pair
    const int r0 = pg * 2;

    float acc[4][16];                    // [o][row*8+col]
#pragma unroll
    for (int j = 0; j < 4; ++j)
#pragma unroll
        for (int i = 0; i < 16; ++i) acc[j][i] = 0.f;

    const float* wrow = W + (size_t)(obase0 + lane) * DD;

    for (int c0 = 0; c0 < CIN; c0 += CCH) {
        __syncthreads();                 // 1 wave: compiles to waitcnt only
        // stage W transposed: lane o' reads its 36 chunk-floats (9 dwordx4),
        // scatters to sW[d][o'] (2-way bank = free)
#pragma unroll
        for (int i = 0; i < 9; ++i) {
            float4 w4 = *(const float4*)(wrow + c0 * 9 + i * 4);
            sW[(i * 4 + 0) * 64 + lane] = w4.x;
            sW[(i * 4 + 1) * 64 + lane] = w4.y;
            sW[(i * 4 + 2) * 64 + lane] = w4.z;
            sW[(i * 4 + 3) * 64 + lane] = w4.w;
        }
        // stage x: 4 cc x 10 halo rows x 10 cols = 400 elems
        for (int t = lane; t < CCH * HR * 10; t += 64) {
            int cc  = t / (HR * 10);
            int rem = t - cc * (HR * 10);
            int h   = rem / 10;
            int s   = rem - h * 10;
            int gy = y0 + h - 1, gx = x0 + s - 1;
            float v = 0.f;
            if ((unsigned)gy < HH && (unsigned)gx < WW)
                v = x[((size_t)(b * CIN + c0 + cc) * HH + gy) * WW + gx];
            sX[cc * (HR * XSTR) + h * XSTR + s] = v;
        }
        __syncthreads();
#pragma unroll
        for (int cc = 0; cc < CCH; ++cc) {
            float xr[4][10];             // halo rows r0..r0+3
#pragma unroll
            for (int t = 0; t < 4; ++t) {
                const float* p = &sX[cc * (HR * XSTR) + (r0 + t) * XSTR];
                float4 a  = *(const float4*)(p);
                float4 bq = *(const float4*)(p + 4);
                float2 c2 = *(const float2*)(p + 8);
                xr[t][0] = a.x;  xr[t][1] = a.y;  xr[t][2] = a.z;  xr[t][3] = a.w;
                xr[t][4] = bq.x; xr[t][5] = bq.y; xr[t][6] = bq.z; xr[t][7] = bq.w;
                xr[t][8] = c2.x; xr[t][9] = c2.y;
            }
#pragma unroll
            for (int u = 0; u < 3; ++u)
#pragma unroll
                for (int v = 0; v < 3; ++v) {
                    float4 w4 = *(const float4*)&sW[(cc * 9 + u * 3 + v) * 64 + og * 4];
                    float wv[4] = {w4.x, w4.y, w4.z, w4.w};
#pragma unroll
                    for (int j = 0; j < 4; ++j)
#pragma unroll
                        for (int r = 0; r < 2; ++r)
#pragma unroll
                            for (int i = 0; i < 8; ++i)
                                acc[j][r * 8 + i] =
                                    fmaf(wv[j], xr[u + r][v + i], acc[j][r * 8 + i]);
                }
        }
    }

#pragma unroll
    for (int j = 0; j < 4; ++j) {
        const int o = obase0 + og * 4 + j;
        const float bz2 = bias[o];
#pragma unroll
        for (int r = 0; r < 2; ++r) {
            const int py = y0 + r0 + r;
            const size_t rowoff = ((size_t)(b * COUT + o) * HH + py) * WW + x0;
            float res[8];
#pragma unroll
            for (int i = 0; i < 8; ++i) {
                float z = acc[j][r * 8 + i] + bz2;
                float q = rintf(__fmul_rn(z, 0.63661975f));   // round(z*2/pi)
                float rr = fmaf(q, -1.5707964f, z);           // z - q*pi/2
                float d = fabsf(fabsf(rr) - 0.78539816f);     // dist to boundary
                res[i] = (d < MARGIN) ? SENT : (float)(((int)q) & 1);
            }
            *(float4*)(out + rowoff)     = make_float4(res[0], res[1], res[2], res[3]);
            *(float4*)(out + rowoff + 4) = make_float4(res[4], res[5], res[6], res[7]);
        }
    }
}

// ---- sentinel scan + bit-exact replay of the verified R9 reference path ----
__global__ __launch_bounds__(256)
void exact_fix(const float* __restrict__ x,
               const float* __restrict__ Wt,
               const float* __restrict__ bias,
               float* __restrict__ out) {
#pragma clang fp contract(off)
    int idx = blockIdx.x * 256 + threadIdx.x;
    if (idx >= TOTAL) return;
    if (out[idx] != SENT) return;        // coalesced scan; rare (~2.5e-4) hit

    int px = idx % WW;
    unsigned t = idx / WW;
    int py = t % HH;  t /= HH;
    int o  = t % COUT;
    int b  = t / COUT;

    const float* wrow = Wt + (size_t)o * DD;
    const float* xb   = x + (size_t)b * CIN * HH * WW;

    int  voff[9];
    bool vok[9];
#pragma unroll
    for (int u = 0; u < 3; ++u)
#pragma unroll
        for (int v = 0; v < 3; ++v) {
            int gy = py + u - 1, gx = px + v - 1;
            vok[u * 3 + v]  = ((unsigned)gy < HH) && ((unsigned)gx < WW);
            voff[u * 3 + v] = gy * WW + gx;
        }

    float accA = 0.f, accB2 = 0.f;        // kc=384-split sequential FMA chains
    for (int c = 0; c < CIN; ++c) {
        const float* xc = xb + c * (HH * WW);
        const float* wc = wrow + c * 9;
        int dbase = c * 9;
#pragma unroll
        for (int tp = 0; tp < 9; ++tp) {
            float p = vok[tp] ? xc[voff[tp]] : 0.f;
            float w = wc[tp];
            if (dbase + tp < KC) accA  = fmaf(p, w, accA);
            else                 accB2 = fmaf(p, w, accB2);
        }
    }
    float zG = __fadd_rn(accA, accB2);
    float z  = __fadd_rn(zG, bias[o]);
    out[idx] = (float)dec_np(z);
}

extern "C" void kernel_launch(void* const* d_in, const int* in_sizes, int n_in,
                              void* d_out, int out_size, void* d_ws, size_t ws_size,
                              hipStream_t stream) {
    const float* x  = (const float*)d_in[0];
    const float* Wt = (const float*)d_in[1];
    const float* bb = (const float*)d_in[2];
    float* out = (float*)d_out;

    fast_conv<<<dim3(7, 7, 64), dim3(64), 0, stream>>>(x, Wt, bb, out);
    exact_fix<<<dim3((TOTAL + 255) / 256), dim3(256), 0, stream>>>(x, Wt, bb, out);
}

// Round 15
// 371.684 us; speedup vs baseline: 3.2648x; 1.1037x over previous
//
#include <hip/hip_runtime.h>
#include <math.h>

// B=32, Cin=64, H=W=56, Cout=128, K=3 pad=1 -> D=576, out (32,128,56,56) fp32
#define B_    32
#define CIN   64
#define HH    56
#define WW    56
#define COUT  128
#define DD    576
#define KC    384            // OpenBLAS kc split (verified R9)
#define LPX   (HH*WW)        // 3136
#define TOTAL (B_*COUT*LPX)
#define MARGIN 4e-4f         // worst-case split-bf16 + reorder error bound 2.7e-4
#define SENT   2.0f          // sentinel marking borderline elements in out

typedef __attribute__((ext_vector_type(8)))  short  short8;
typedef __attribute__((ext_vector_type(16))) float  float16v;

__device__ __forceinline__ unsigned short bf16_rne(float f) {
    unsigned u = __float_as_uint(f);
    unsigned r = u + 0x7FFFu + ((u >> 16) & 1u);
    return (unsigned short)(r >> 16);
}
__device__ __forceinline__ float bf16_to_f(unsigned short h) {
    return __uint_as_float(((unsigned)h) << 16);
}

// ---- bit-exact numpy FLOAT_sin (npyv FMA path) — verified R9 ----
__device__ __forceinline__ float np_sinf(float x) {
#pragma clang fp contract(off)
    const float rint_cvt = 0x1.8p+23f;
    float q = __fmul_rn(x, 0x1.45f306p-1f);
    q = __fadd_rn(q, rint_cvt);
    q = __fsub_rn(q, rint_cvt);
    float r = fmaf(q, -0x1.921fb0p+0f, x);
    r = fmaf(q, -0x1.5110b4p-22f, r);
    r = fmaf(q, -0x1.846988p-48f, r);
    float r2 = __fmul_rn(r, r);
    float s = fmaf(0x1.7d3bbcp-19f, r2, -0x1.a06bbap-13f);
    s = fmaf(s, r2, 0x1.11119ap-7f);
    s = fmaf(s, r2, -0x1.555556p-3f);
    s = __fmul_rn(s, r2);
    s = fmaf(s, r, r);
    float c = fmaf(0x1.98e616p-16f, r2, -0x1.6c06dcp-10f);
    c = fmaf(c, r2, 0x1.55553cp-5f);
    c = fmaf(c, r2, -0.5f);
    c = fmaf(c, r2, 1.0f);
    int iq = (int)q;
    float res = (iq & 1) ? c : s;
    unsigned sgn = ((unsigned)(iq & 2)) << 30;
    return __uint_as_float(__float_as_uint(res) ^ sgn);
}

__device__ __forceinline__ int dec_np(float z) {
    float s = np_sinf(z);
    return (__fmul_rn(s, s) > 0.5f) ? 1 : 0;
}

// ---- prep: split W into bf16 hi/lo (once per launch; ws re-poisoned) ----
__global__ __launch_bounds__(256)
void prep_w(const float* __restrict__ W, unsigned short* __restrict__ Wh,
            unsigned short* __restrict__ Wl) {
    int i = blockIdx.x * 256 + threadIdx.x;
    if (i >= COUT * DD) return;
    float w = W[i];
    unsigned short h = bf16_rne(w);
    Wh[i] = h;
    Wl[i] = bf16_rne(w - bf16_to_f(h));
}

// ---- MFMA conv: block = 128 o x 128 flat-px, 4 waves (64o x 64px each) ----
// 3-pass split-bf16: acc += Wh*Xh + Wh*Xl + Wl*Xh  (error <= 2.7e-4 worst-case)
// A[m=lane&31][k=(lane>>5)*8+j]; B[k][n=lane&31]; D row=(reg&3)+8(reg>>2)+4(lane>>5)
__global__ __launch_bounds__(256, 3)
void conv_mfma(const float* __restrict__ x,
               const unsigned short* __restrict__ Whg,
               const unsigned short* __restrict__ Wlg,
               const float* __restrict__ bias,
               float* __restrict__ out) {
    __shared__ __align__(16) unsigned short sWh[COUT * 32];   // [o][dloc] 8 KB
    __shared__ __align__(16) unsigned short sWl[COUT * 32];
    __shared__ __align__(16) unsigned short sPh[128 * 32];    // [px][dloc] 8 KB
    __shared__ __align__(16) unsigned short sPl[128 * 32];

    const int tid = threadIdx.x;
    const int pt0 = blockIdx.x * 128;    // flat-px tile base (0..24*128)
    const int b   = blockIdx.y;

    // staging precompute: thread owns d-pair slot `pair`, px slots pxb+16r
    const int pair = tid & 15;
    const int pxb  = tid >> 4;
    int ypx[8], xpx[8], vpx[8];
#pragma unroll
    for (int r = 0; r < 8; ++r) {
        int pxg = pt0 + pxb + r * 16;
        ypx[r] = pxg / WW;
        xpx[r] = pxg - ypx[r] * WW;
        vpx[r] = (pxg < LPX) ? 1 : 0;
    }
    const float* xb = x + (size_t)b * CIN * LPX;

    const int w    = tid >> 6;
    const int lane = tid & 63;
    const int lm   = lane & 31;
    const int half = lane >> 5;
    const int m0w  = (w >> 1) * 64;      // o base of wave
    const int n0w  = (w & 1) * 64;       // px base of wave (within tile)

    float16v acc[2][2];
#pragma unroll
    for (int a = 0; a < 2; ++a)
#pragma unroll
        for (int n = 0; n < 2; ++n)
#pragma unroll
            for (int i = 0; i < 16; ++i) acc[a][n][i] = 0.f;

    for (int k0 = 0; k0 < DD; k0 += 32) {
        __syncthreads();
        // stage W hi/lo: thread -> (o = tid>>1, hf = tid&1), 16 bf16 = 2 uint4
        {
            int o = tid >> 1, hf = tid & 1;
            const uint4* sh = (const uint4*)(Whg + (size_t)o * DD + k0 + hf * 16);
            const uint4* sl = (const uint4*)(Wlg + (size_t)o * DD + k0 + hf * 16);
            uint4* dh = (uint4*)(sWh + o * 32 + hf * 16);
            uint4* dl = (uint4*)(sWl + o * 32 + hf * 16);
            dh[0] = sh[0]; dh[1] = sh[1];
            dl[0] = sl[0]; dl[1] = sl[1];
        }
        // stage P hi/lo: gather fp32 x, split, pack d-pairs as b32 writes
        {
            int d0 = k0 + pair * 2;
            int c0 = d0 / 9, t0 = d0 - c0 * 9;
            int u0 = t0 / 3, v0 = t0 - u0 * 3;
            int t1 = t0 + 1, c1 = c0;
            if (t1 == 9) { t1 = 0; c1 = c0 + 1; }
            int u1 = t1 / 3, v1 = t1 - u1 * 3;
            int base0 = c0 * LPX + (u0 - 1) * WW + (v0 - 1);
            int base1 = c1 * LPX + (u1 - 1) * WW + (v1 - 1);
#pragma unroll
            for (int r = 0; r < 8; ++r) {
                int gy0 = ypx[r] + u0 - 1, gx0 = xpx[r] + v0 - 1;
                int gy1 = ypx[r] + u1 - 1, gx1 = xpx[r] + v1 - 1;
                int pxoff = ypx[r] * WW + xpx[r];
                float f0 = (vpx[r] && (unsigned)gy0 < HH && (unsigned)gx0 < WW)
                               ? xb[base0 + pxoff] : 0.f;
                float f1 = (vpx[r] && (unsigned)gy1 < HH && (unsigned)gx1 < WW)
                               ? xb[base1 + pxoff] : 0.f;
                unsigned short h0 = bf16_rne(f0);
                unsigned short h1 = bf16_rne(f1);
                unsigned short l0 = bf16_rne(f0 - bf16_to_f(h0));
                unsigned short l1 = bf16_rne(f1 - bf16_to_f(h1));
                int word = (pxb + r * 16) * 16 + pair;
                ((unsigned*)sPh)[word] = (unsigned)h0 | ((unsigned)h1 << 16);
                ((unsigned*)sPl)[word] = (unsigned)l0 | ((unsigned)l1 << 16);
            }
        }
        __syncthreads();
#pragma unroll
        for (int s = 0; s < 2; ++s) {
            short8 Ah[2], Al[2], Bh[2], Bl[2];
#pragma unroll
            for (int a = 0; a < 2; ++a) {
                int off = (m0w + a * 32 + lm) * 32 + s * 16 + half * 8;
                Ah[a] = *(const short8*)(sWh + off);
                Al[a] = *(const short8*)(sWl + off);
            }
#pragma unroll
            for (int n = 0; n < 2; ++n) {
                int off = (n0w + n * 32 + lm) * 32 + s * 16 + half * 8;
                Bh[n] = *(const short8*)(sPh + off);
                Bl[n] = *(const short8*)(sPl + off);
            }
#pragma unroll
            for (int a = 0; a < 2; ++a)
#pragma unroll
                for (int n = 0; n < 2; ++n)
                    acc[a][n] = __builtin_amdgcn_mfma_f32_32x32x16_bf16(
                        Ah[a], Bh[n], acc[a][n], 0, 0, 0);
#pragma unroll
            for (int a = 0; a < 2; ++a)
#pragma unroll
                for (int n = 0; n < 2; ++n)
                    acc[a][n] = __builtin_amdgcn_mfma_f32_32x32x16_bf16(
                        Ah[a], Bl[n], acc[a][n], 0, 0, 0);
#pragma unroll
            for (int a = 0; a < 2; ++a)
#pragma unroll
                for (int n = 0; n < 2; ++n)
                    acc[a][n] = __builtin_amdgcn_mfma_f32_32x32x16_bf16(
                        Al[a], Bh[n], acc[a][n], 0, 0, 0);
        }
    }

    // epilogue: bias + parity decision + sentinel for borderline
    const size_t outb = (size_t)b * COUT * LPX;
#pragma unroll
    for (int a = 0; a < 2; ++a) {
        const int obase = m0w + a * 32 + 4 * half;
        float bz[16];
#pragma unroll
        for (int reg = 0; reg < 16; ++reg)
            bz[reg] = bias[obase + (reg & 3) + 8 * (reg >> 2)];
#pragma unroll
        for (int n = 0; n < 2; ++n) {
            if (pt0 + n0w + n * 32 >= LPX) continue;   // uniform tile mask
            const int pxg = pt0 + n0w + n * 32 + lm;
#pragma unroll
            for (int reg = 0; reg < 16; ++reg) {
                int o = obase + (reg & 3) + 8 * (reg >> 2);
                float z = acc[a][n][reg] + bz[reg];
                float q = rintf(__fmul_rn(z, 0.63661975f));   // round(z*2/pi)
                float rr = fmaf(q, -1.5707964f, z);
                float d = fabsf(fabsf(rr) - 0.78539816f);     // dist to boundary
                float res = (d < MARGIN) ? SENT : (float)(((int)q) & 1);
                out[outb + (size_t)o * LPX + pxg] = res;
            }
        }
    }
}

// ---- sentinel scan (float4) + bit-exact replay of verified R9 path ----
__global__ __launch_bounds__(256)
void exact_fix(const float* __restrict__ x,
               const float* __restrict__ Wt,
               const float* __restrict__ bias,
               float* __restrict__ out) {
#pragma clang fp contract(off)
    int q4 = blockIdx.x * 256 + threadIdx.x;
    if (q4 * 4 >= TOTAL) return;
    float4 v = *(const float4*)(out + (size_t)q4 * 4);
    float vv[4] = {v.x, v.y, v.z, v.w};
#pragma unroll
    for (int e = 0; e < 4; ++e) {
        if (vv[e] != SENT) continue;
        int idx = q4 * 4 + e;
        int px = idx % WW;
        unsigned t = idx / WW;
        int py = t % HH;  t /= HH;
        int o  = t % COUT;
        int b  = t / COUT;

        const float* wrow = Wt + (size_t)o * DD;
        const float* xb   = x + (size_t)b * CIN * LPX;

        int  voff[9];
        bool vok[9];
#pragma unroll
        for (int u = 0; u < 3; ++u)
#pragma unroll
            for (int vv2 = 0; vv2 < 3; ++vv2) {
                int gy = py + u - 1, gx = px + vv2 - 1;
                vok[u * 3 + vv2]  = ((unsigned)gy < HH) && ((unsigned)gx < WW);
                voff[u * 3 + vv2] = gy * WW + gx;
            }

        float accA = 0.f, accB2 = 0.f;    // kc=384-split sequential FMA chains
        for (int c = 0; c < CIN; ++c) {
            const float* xc = xb + c * LPX;
            const float* wc = wrow + c * 9;
            int dbase = c * 9;
#pragma unroll
            for (int tp = 0; tp < 9; ++tp) {
                float p = vok[tp] ? xc[voff[tp]] : 0.f;
                float wv = wc[tp];
                if (dbase + tp < KC) accA  = fmaf(p, wv, accA);
                else                 accB2 = fmaf(p, wv, accB2);
            }
        }
        float zG = __fadd_rn(accA, accB2);
        float z  = __fadd_rn(zG, bias[o]);
        out[idx] = (float)dec_np(z);
    }
}

// ---- fallback (verified R9 path) if workspace is unexpectedly tiny ----
__global__ __launch_bounds__(256)
void np_emul_conv(const float* __restrict__ x,
                  const float* __restrict__ Wt,
                  const float* __restrict__ bias,
                  float* __restrict__ out) {
#pragma clang fp contract(off)
    int idx = blockIdx.x * 256 + threadIdx.x;
    if (idx >= TOTAL) return;
    int px = idx % WW;
    int t  = idx / WW;
    int py = t % HH;  t /= HH;
    int o  = t % COUT;
    int b  = t / COUT;
    const float* wrow = Wt + (size_t)o * DD;
    const float* xb   = x + (size_t)b * CIN * LPX;
    float accA = 0.f, accB2 = 0.f;
    for (int c = 0; c < CIN; ++c) {
        const float* xc = xb + c * LPX;
        const float* wc = wrow + c * 9;
        int dbase = c * 9;
#pragma unroll
        for (int u = 0; u < 3; ++u)
#pragma unroll
            for (int v = 0; v < 3; ++v) {
                int tp = u * 3 + v;
                int gy = py + u - 1, gx = px + v - 1;
                float p = ((unsigned)gy < HH && (unsigned)gx < WW) ? xc[gy * WW + gx] : 0.f;
                if (dbase + tp < KC) accA  = fmaf(p, wc[tp], accA);
                else                 accB2 = fmaf(p, wc[tp], accB2);
            }
    }
    float z = __fadd_rn(__fadd_rn(accA, accB2), bias[o]);
    out[idx] = (float)dec_np(z);
}

extern "C" void kernel_launch(void* const* d_in, const int* in_sizes, int n_in,
                              void* d_out, int out_size, void* d_ws, size_t ws_size,
                              hipStream_t stream) {
    const float* x  = (const float*)d_in[0];
    const float* Wt = (const float*)d_in[1];
    const float* bb = (const float*)d_in[2];
    float* out = (float*)d_out;

    const size_t WSPLIT = (size_t)COUT * DD * 2;     // 147456 B per array
    if (ws_size < 2 * WSPLIT) {                      // fallback: verified R9 path
        np_emul_conv<<<(TOTAL + 255) / 256, 256, 0, stream>>>(x, Wt, bb, out);
        return;
    }
    unsigned short* Whg = (unsigned short*)d_ws;
    unsigned short* Wlg = Whg + COUT * DD;

    prep_w<<<dim3((COUT * DD + 255) / 256), dim3(256), 0, stream>>>(Wt, Whg, Wlg);
    conv_mfma<<<dim3(25, B_), dim3(256), 0, stream>>>(x, Whg, Wlg, bb, out);
    exact_fix<<<dim3((TOTAL / 4 + 255) / 256), dim3(256), 0, stream>>>(x, Wt, bb, out);
}

// Round 16
// 350.301 us; speedup vs baseline: 3.4641x; 1.0610x over previous
//
#include <hip/hip_runtime.h>
#include <math.h>

// B=32, Cin=64, H=W=56, Cout=128, K=3 pad=1 -> D=576, out (32,128,56,56) fp32
#define B_    32
#define CIN   64
#define HH    56
#define WW    56
#define COUT  128
#define DD    576
#define KC    384            // OpenBLAS kc split (verified R9)
#define LPX   (HH*WW)        // 3136
#define TOTAL (B_*COUT*LPX)
#define MARGIN 4e-4f         // worst-case split-bf16 + reorder error bound (validated R15)
#define SENT   2.0f          // sentinel marking borderline elements in out

typedef __attribute__((ext_vector_type(8)))  short  short8;
typedef __attribute__((ext_vector_type(16))) float  float16v;

__device__ __forceinline__ unsigned short bf16_rne(float f) {
    unsigned u = __float_as_uint(f);
    unsigned r = u + 0x7FFFu + ((u >> 16) & 1u);
    return (unsigned short)(r >> 16);
}
__device__ __forceinline__ float bf16_to_f(unsigned short h) {
    return __uint_as_float(((unsigned)h) << 16);
}

// ---- bit-exact numpy FLOAT_sin (npyv FMA path) — verified R9 ----
__device__ __forceinline__ float np_sinf(float x) {
#pragma clang fp contract(off)
    const float rint_cvt = 0x1.8p+23f;
    float q = __fmul_rn(x, 0x1.45f306p-1f);
    q = __fadd_rn(q, rint_cvt);
    q = __fsub_rn(q, rint_cvt);
    float r = fmaf(q, -0x1.921fb0p+0f, x);
    r = fmaf(q, -0x1.5110b4p-22f, r);
    r = fmaf(q, -0x1.846988p-48f, r);
    float r2 = __fmul_rn(r, r);
    float s = fmaf(0x1.7d3bbcp-19f, r2, -0x1.a06bbap-13f);
    s = fmaf(s, r2, 0x1.11119ap-7f);
    s = fmaf(s, r2, -0x1.555556p-3f);
    s = __fmul_rn(s, r2);
    s = fmaf(s, r, r);
    float c = fmaf(0x1.98e616p-16f, r2, -0x1.6c06dcp-10f);
    c = fmaf(c, r2, 0x1.55553cp-5f);
    c = fmaf(c, r2, -0.5f);
    c = fmaf(c, r2, 1.0f);
    int iq = (int)q;
    float res = (iq & 1) ? c : s;
    unsigned sgn = ((unsigned)(iq & 2)) << 30;
    return __uint_as_float(__float_as_uint(res) ^ sgn);
}

__device__ __forceinline__ int dec_np(float z) {
    float s = np_sinf(z);
    return (__fmul_rn(s, s) > 0.5f) ? 1 : 0;
}

// ---- prep: split W into bf16 hi/lo ----
__global__ __launch_bounds__(256)
void prep_w(const float* __restrict__ W, unsigned short* __restrict__ Wh,
            unsigned short* __restrict__ Wl) {
    int i = blockIdx.x * 256 + threadIdx.x;
    if (i >= COUT * DD) return;
    float w = W[i];
    unsigned short h = bf16_rne(w);
    Wh[i] = h;
    Wl[i] = bf16_rne(w - bf16_to_f(h));
}

// ---- MFMA conv: block = 128 o x 128 flat-px, 4 waves (64o x 64px each) ----
// Fragment-major LDS layout [tile32][s][half][lane][j] -> all ds_read_b128 at
// the conflict-free wave64 floor; gather mapping px=tid&15 -> coalesced loads.
// 3-pass split-bf16: acc += Wh*Xh + Wh*Xl + Wl*Xh (validated R15).
#define FRAG(t, s, hf, ln)  (((t) * 1024) + ((s) * 512) + ((hf) * 256) + ((ln) * 8))
__global__ __launch_bounds__(256, 3)
void conv_mfma(const float* __restrict__ x,
               const unsigned short* __restrict__ Whg,
               const unsigned short* __restrict__ Wlg,
               const float* __restrict__ bias,
               float* __restrict__ out) {
    __shared__ __align__(16) unsigned short sWh[4096];   // 8 KB each
    __shared__ __align__(16) unsigned short sWl[4096];
    __shared__ __align__(16) unsigned short sPh[4096];
    __shared__ __align__(16) unsigned short sPl[4096];

    const int tid = threadIdx.x;
    const int pt0 = blockIdx.x * 128;    // flat-px tile base
    const int b   = blockIdx.y;

    // ---- staging ids ----
    const int plane = tid & 15;          // px lane (consecutive px -> coalesced)
    const int pair  = tid >> 4;          // d-pair 0..15
    const int s_st  = pair >> 3;         // k16 step of this pair
    const int h_st  = (pair >> 2) & 1;   // half
    const int j2_st = pair & 3;          // word offset within fragment
    int ypx[8], xpx[8], vpx[8];
#pragma unroll
    for (int r = 0; r < 8; ++r) {
        int pxg = pt0 + plane + r * 16;
        ypx[r] = pxg / WW;
        xpx[r] = pxg - ypx[r] * WW;
        vpx[r] = (pxg < LPX) ? 1 : 0;
    }
    const float* xb = x + (size_t)b * CIN * LPX;
    const int wo  = tid >> 1;            // W staging: o
    const int whf = tid & 1;             // W staging: k16 half of chunk
    const int wot = wo >> 5, wom = wo & 31;

    // ---- compute ids ----
    const int w    = tid >> 6;
    const int lane = tid & 63;
    const int lm   = lane & 31;
    const int half = lane >> 5;
    const int m0w  = (w >> 1) * 64;      // o base of wave
    const int n0w  = (w & 1) * 64;       // px base of wave (within tile)

    float16v acc[2][2];
#pragma unroll
    for (int a = 0; a < 2; ++a)
#pragma unroll
        for (int n = 0; n < 2; ++n)
#pragma unroll
            for (int i = 0; i < 16; ++i) acc[a][n][i] = 0.f;

    for (int k0 = 0; k0 < DD; k0 += 32) {
        __syncthreads();
        // stage W hi/lo: fragment-major
        {
            const uint4* sh = (const uint4*)(Whg + (size_t)wo * DD + k0 + whf * 16);
            const uint4* sl = (const uint4*)(Wlg + (size_t)wo * DD + k0 + whf * 16);
            uint4 h0 = sh[0], h1 = sh[1];
            uint4 l0 = sl[0], l1 = sl[1];
            *(uint4*)(sWh + FRAG(wot, whf, 0, wom)) = h0;
            *(uint4*)(sWh + FRAG(wot, whf, 1, wom)) = h1;
            *(uint4*)(sWl + FRAG(wot, whf, 0, wom)) = l0;
            *(uint4*)(sWl + FRAG(wot, whf, 1, wom)) = l1;
        }
        // stage P hi/lo: coalesced gather, split, packed b32 writes
        {
            int d0 = k0 + pair * 2;
            int c0 = d0 / 9, t0 = d0 - c0 * 9;
            int u0 = t0 / 3, v0 = t0 - u0 * 3;
            int t1 = t0 + 1, c1 = c0;
            if (t1 == 9) { t1 = 0; c1 = c0 + 1; }
            int u1 = t1 / 3, v1 = t1 - u1 * 3;
            int base0 = c0 * LPX + (u0 - 1) * WW + (v0 - 1);
            int base1 = c1 * LPX + (u1 - 1) * WW + (v1 - 1);
#pragma unroll
            for (int r = 0; r < 8; ++r) {
                int gy0 = ypx[r] + u0 - 1, gx0 = xpx[r] + v0 - 1;
                int gy1 = ypx[r] + u1 - 1, gx1 = xpx[r] + v1 - 1;
                int pxoff = ypx[r] * WW + xpx[r];
                float f0 = (vpx[r] && (unsigned)gy0 < HH && (unsigned)gx0 < WW)
                               ? xb[base0 + pxoff] : 0.f;
                float f1 = (vpx[r] && (unsigned)gy1 < HH && (unsigned)gx1 < WW)
                               ? xb[base1 + pxoff] : 0.f;
                unsigned short h0 = bf16_rne(f0);
                unsigned short h1 = bf16_rne(f1);
                unsigned short l0 = bf16_rne(f0 - bf16_to_f(h0));
                unsigned short l1 = bf16_rne(f1 - bf16_to_f(h1));
                int pm = plane + (r & 1) * 16;     // px & 31
                int word = ((r >> 1) * 512 + s_st * 256 + h_st * 128 + pm * 4 + j2_st);
                ((unsigned*)sPh)[word] = (unsigned)h0 | ((unsigned)h1 << 16);
                ((unsigned*)sPl)[word] = (unsigned)l0 | ((unsigned)l1 << 16);
            }
        }
        __syncthreads();
#pragma unroll
        for (int s = 0; s < 2; ++s) {
            short8 Ah[2], Al[2], Bh[2], Bl[2];
#pragma unroll
            for (int a = 0; a < 2; ++a) {
                int ot = (w >> 1) * 2 + a;
                Ah[a] = *(const short8*)(sWh + FRAG(ot, s, half, lm));
                Al[a] = *(const short8*)(sWl + FRAG(ot, s, half, lm));
            }
#pragma unroll
            for (int n = 0; n < 2; ++n) {
                int pt = (w & 1) * 2 + n;
                Bh[n] = *(const short8*)(sPh + FRAG(pt, s, half, lm));
                Bl[n] = *(const short8*)(sPl + FRAG(pt, s, half, lm));
            }
#pragma unroll
            for (int a = 0; a < 2; ++a)
#pragma unroll
                for (int n = 0; n < 2; ++n)
                    acc[a][n] = __builtin_amdgcn_mfma_f32_32x32x16_bf16(
                        Ah[a], Bh[n], acc[a][n], 0, 0, 0);
#pragma unroll
            for (int a = 0; a < 2; ++a)
#pragma unroll
                for (int n = 0; n < 2; ++n)
                    acc[a][n] = __builtin_amdgcn_mfma_f32_32x32x16_bf16(
                        Ah[a], Bl[n], acc[a][n], 0, 0, 0);
#pragma unroll
            for (int a = 0; a < 2; ++a)
#pragma unroll
                for (int n = 0; n < 2; ++n)
                    acc[a][n] = __builtin_amdgcn_mfma_f32_32x32x16_bf16(
                        Al[a], Bh[n], acc[a][n], 0, 0, 0);
        }
    }

    // epilogue: bias + parity decision + sentinel for borderline
    const size_t outb = (size_t)b * COUT * LPX;
#pragma unroll
    for (int a = 0; a < 2; ++a) {
        const int obase = m0w + a * 32 + 4 * half;
        float bz[16];
#pragma unroll
        for (int reg = 0; reg < 16; ++reg)
            bz[reg] = bias[obase + (reg & 3) + 8 * (reg >> 2)];
#pragma unroll
        for (int n = 0; n < 2; ++n) {
            if (pt0 + n0w + n * 32 >= LPX) continue;   // 32-tiles align with 3136
            const int pxg = pt0 + n0w + n * 32 + lm;
#pragma unroll
            for (int reg = 0; reg < 16; ++reg) {
                int o = obase + (reg & 3) + 8 * (reg >> 2);
                float z = acc[a][n][reg] + bz[reg];
                float q = rintf(__fmul_rn(z, 0.63661975f));   // round(z*2/pi)
                float rr = fmaf(q, -1.5707964f, z);
                float d = fabsf(fabsf(rr) - 0.78539816f);     // dist to boundary
                float res = (d < MARGIN) ? SENT : (float)(((int)q) & 1);
                out[outb + (size_t)o * LPX + pxg] = res;
            }
        }
    }
}

// ---- sentinel scan (float4) + bit-exact replay of verified R9 path ----
__global__ __launch_bounds__(256)
void exact_fix(const float* __restrict__ x,
               const float* __restrict__ Wt,
               const float* __restrict__ bias,
               float* __restrict__ out) {
#pragma clang fp contract(off)
    int q4 = blockIdx.x * 256 + threadIdx.x;
    if (q4 * 4 >= TOTAL) return;
    float4 v = *(const float4*)(out + (size_t)q4 * 4);
    float vv[4] = {v.x, v.y, v.z, v.w};
#pragma unroll
    for (int e = 0; e < 4; ++e) {
        if (vv[e] != SENT) continue;
        int idx = q4 * 4 + e;
        int px = idx % WW;
        unsigned t = idx / WW;
        int py = t % HH;  t /= HH;
        int o  = t % COUT;
        int b  = t / COUT;

        const float* wrow = Wt + (size_t)o * DD;
        const float* xb   = x + (size_t)b * CIN * LPX;

        int  voff[9];
        bool vok[9];
#pragma unroll
        for (int u = 0; u < 3; ++u)
#pragma unroll
            for (int vv2 = 0; vv2 < 3; ++vv2) {
                int gy = py + u - 1, gx = px + vv2 - 1;
                vok[u * 3 + vv2]  = ((unsigned)gy < HH) && ((unsigned)gx < WW);
                voff[u * 3 + vv2] = gy * WW + gx;
            }

        float accA = 0.f, accB2 = 0.f;    // kc=384-split sequential FMA chains
        for (int c = 0; c < CIN; ++c) {
            const float* xc = xb + c * LPX;
            const float* wc = wrow + c * 9;
            int dbase = c * 9;
#pragma unroll
            for (int tp = 0; tp < 9; ++tp) {
                float p = vok[tp] ? xc[voff[tp]] : 0.f;
                float wv = wc[tp];
                if (dbase + tp < KC) accA  = fmaf(p, wv, accA);
                else                 accB2 = fmaf(p, wv, accB2);
            }
        }
        float zG = __fadd_rn(accA, accB2);
        float z  = __fadd_rn(zG, bias[o]);
        out[idx] = (float)dec_np(z);
    }
}

// ---- fallback (verified R9 path) if workspace is unexpectedly tiny ----
__global__ __launch_bounds__(256)
void np_emul_conv(const float* __restrict__ x,
                  const float* __restrict__ Wt,
                  const float* __restrict__ bias,
                  float* __restrict__ out) {
#pragma clang fp contract(off)
    int idx = blockIdx.x * 256 + threadIdx.x;
    if (idx >= TOTAL) return;
    int px = idx % WW;
    int t  = idx / WW;
    int py = t % HH;  t /= HH;
    int o  = t % COUT;
    int b  = t / COUT;
    const float* wrow = Wt + (size_t)o * DD;
    const float* xb   = x + (size_t)b * CIN * LPX;
    float accA = 0.f, accB2 = 0.f;
    for (int c = 0; c < CIN; ++c) {
        const float* xc = xb + c * LPX;
        const float* wc = wrow + c * 9;
        int dbase = c * 9;
#pragma unroll
        for (int u = 0; u < 3; ++u)
#pragma unroll
            for (int v = 0; v < 3; ++v) {
                int tp = u * 3 + v;
                int gy = py + u - 1, gx = px + v - 1;
                float p = ((unsigned)gy < HH && (unsigned)gx < WW) ? xc[gy * WW + gx] : 0.f;
                if (dbase + tp < KC) accA  = fmaf(p, wc[tp], accA);
                else                 accB2 = fmaf(p, wc[tp], accB2);
            }
    }
    float z = __fadd_rn(__fadd_rn(accA, accB2), bias[o]);
    out[idx] = (float)dec_np(z);
}

extern "C" void kernel_launch(void* const* d_in, const int* in_sizes, int n_in,
                              void* d_out, int out_size, void* d_ws, size_t ws_size,
                              hipStream_t stream) {
    const float* x  = (const float*)d_in[0];
    const float* Wt = (const float*)d_in[1];
    const float* bb = (const float*)d_in[2];
    float* out = (float*)d_out;

    const size_t WSPLIT = (size_t)COUT * DD * 2;     // 147456 B per array
    if (ws_size < 2 * WSPLIT) {                      // fallback: verified R9 path
        np_emul_conv<<<(TOTAL + 255) / 256, 256, 0, stream>>>(x, Wt, bb, out);
        return;
    }
    unsigned short* Whg = (unsigned short*)d_ws;
    unsigned short* Wlg = Whg + COUT * DD;

    prep_w<<<dim3((COUT * DD + 255) / 256), dim3(256), 0, stream>>>(Wt, Whg, Wlg);
    conv_mfma<<<dim3(25, B_), dim3(256), 0, stream>>>(x, Whg, Wlg, bb, out);
    exact_fix<<<dim3((TOTAL / 4 + 255) / 256), dim3(256), 0, stream>>>(x, Wt, bb, out);
}

// Round 17
// 308.833 us; speedup vs baseline: 3.9292x; 1.1343x over previous
//
#include <hip/hip_runtime.h>
#include <math.h>

// B=32, Cin=64, H=W=56, Cout=128, K=3 pad=1 -> D=576, out (32,128,56,56) fp32
#define B_    32
#define CIN   64
#define HH    56
#define WW    56
#define COUT  128
#define DD    576
#define KC    384            // OpenBLAS kc split (verified R9)
#define LPX   (HH*WW)        // 3136 = 49*64
#define TOTAL (B_*COUT*LPX)
#define NX    (B_*CIN*LPX)   // 6422528
#define MARGIN 4e-4f         // worst-case split-bf16 + reorder bound (validated R15/16)
#define SENT   2.0f

typedef __attribute__((ext_vector_type(8)))  short  short8;
typedef __attribute__((ext_vector_type(16))) float  float16v;

__device__ __forceinline__ unsigned short bf16_rne(float f) {
    unsigned u = __float_as_uint(f);
    unsigned r = u + 0x7FFFu + ((u >> 16) & 1u);
    return (unsigned short)(r >> 16);
}
__device__ __forceinline__ float bf16_to_f(unsigned short h) {
    return __uint_as_float(((unsigned)h) << 16);
}

// ---- bit-exact numpy FLOAT_sin (npyv FMA path) — verified R9 ----
__device__ __forceinline__ float np_sinf(float x) {
#pragma clang fp contract(off)
    const float rint_cvt = 0x1.8p+23f;
    float q = __fmul_rn(x, 0x1.45f306p-1f);
    q = __fadd_rn(q, rint_cvt);
    q = __fsub_rn(q, rint_cvt);
    float r = fmaf(q, -0x1.921fb0p+0f, x);
    r = fmaf(q, -0x1.5110b4p-22f, r);
    r = fmaf(q, -0x1.846988p-48f, r);
    float r2 = __fmul_rn(r, r);
    float s = fmaf(0x1.7d3bbcp-19f, r2, -0x1.a06bbap-13f);
    s = fmaf(s, r2, 0x1.11119ap-7f);
    s = fmaf(s, r2, -0x1.555556p-3f);
    s = __fmul_rn(s, r2);
    s = fmaf(s, r, r);
    float c = fmaf(0x1.98e616p-16f, r2, -0x1.6c06dcp-10f);
    c = fmaf(c, r2, 0x1.55553cp-5f);
    c = fmaf(c, r2, -0.5f);
    c = fmaf(c, r2, 1.0f);
    int iq = (int)q;
    float res = (iq & 1) ? c : s;
    unsigned sgn = ((unsigned)(iq & 2)) << 30;
    return __uint_as_float(__float_as_uint(res) ^ sgn);
}
__device__ __forceinline__ int dec_np(float z) {
    float s = np_sinf(z);
    return (__fmul_rn(s, s) > 0.5f) ? 1 : 0;
}

// ---- prep: split W -> bf16 hi/lo arrays; split x -> interleaved (h|l<<16) ----
__global__ __launch_bounds__(256)
void prep_w(const float* __restrict__ W, unsigned short* __restrict__ Wh,
            unsigned short* __restrict__ Wl) {
    int i = blockIdx.x * 256 + threadIdx.x;
    if (i >= COUT * DD) return;
    float w = W[i];
    unsigned short h = bf16_rne(w);
    Wh[i] = h;
    Wl[i] = bf16_rne(w - bf16_to_f(h));
}
__global__ __launch_bounds__(256)
void prep_x(const float* __restrict__ x, unsigned* __restrict__ xs) {
    int i = blockIdx.x * 256 + threadIdx.x;
    if (i >= NX) return;
    float f = x[i];
    unsigned short h = bf16_rne(f);
    unsigned short l = bf16_rne(f - bf16_to_f(h));
    xs[i] = (unsigned)h | ((unsigned)l << 16);
}

// ---- MFMA conv A: block = 128 o x 64 px, 4 waves (64o x 32px each) ----
// grid 49x32=1568 blocks (6.1/CU), LDS 24KB (6 blocks/CU). Fragment-major LDS
// [tile32][s][half][lane][j]; staging = u32 gathers + 2 perm packs (no float).
#define FRAG(t, s, hf, ln)  (((t) * 1024) + ((s) * 512) + ((hf) * 256) + ((ln) * 8))
__global__ __launch_bounds__(256, 4)
void conv_mfma(const unsigned* __restrict__ xs,
               const unsigned short* __restrict__ Whg,
               const unsigned short* __restrict__ Wlg,
               const float* __restrict__ bias,
               float* __restrict__ out) {
    __shared__ __align__(16) unsigned short sWh[4096];   // 8 KB
    __shared__ __align__(16) unsigned short sWl[4096];   // 8 KB
    __shared__ __align__(16) unsigned short sPh[2048];   // 4 KB
    __shared__ __align__(16) unsigned short sPl[2048];   // 4 KB

    const int tid = threadIdx.x;
    const int pt0 = blockIdx.x * 64;     // px tile base (49*64=3136: exact)
    const int b   = blockIdx.y;

    // staging ids
    const int plane = tid & 15;          // px lane -> coalesced gathers
    const int pair  = tid >> 4;          // d-pair 0..15
    const int s_st  = pair >> 3;
    const int h_st  = (pair >> 2) & 1;
    const int j2_st = pair & 3;
    int ypx[4], xpx[4];
#pragma unroll
    for (int r = 0; r < 4; ++r) {
        int pxg = pt0 + plane + r * 16;
        ypx[r] = pxg / WW;
        xpx[r] = pxg - ypx[r] * WW;
    }
    const unsigned* xb = xs + (size_t)b * CIN * LPX;
    const int wo  = tid >> 1;            // W staging: o 0..127
    const int whf = tid & 1;
    const int wot = wo >> 5, wom = wo & 31;

    // compute ids
    const int w    = tid >> 6;           // wave 0..3
    const int lane = tid & 63;
    const int lm   = lane & 31;
    const int half = lane >> 5;
    const int aw   = w >> 1;             // o half (0..1)
    const int nw   = w & 1;              // px tile (0..1)

    float16v acc[2];
#pragma unroll
    for (int a = 0; a < 2; ++a)
#pragma unroll
        for (int i = 0; i < 16; ++i) acc[a][i] = 0.f;

    for (int k0 = 0; k0 < DD; k0 += 32) {
        __syncthreads();
        // stage W hi/lo (fragment-major)
        {
            const uint4* sh = (const uint4*)(Whg + (size_t)wo * DD + k0 + whf * 16);
            const uint4* sl = (const uint4*)(Wlg + (size_t)wo * DD + k0 + whf * 16);
            uint4 h0 = sh[0], h1 = sh[1];
            uint4 l0 = sl[0], l1 = sl[1];
            *(uint4*)(sWh + FRAG(wot, whf, 0, wom)) = h0;
            *(uint4*)(sWh + FRAG(wot, whf, 1, wom)) = h1;
            *(uint4*)(sWl + FRAG(wot, whf, 0, wom)) = l0;
            *(uint4*)(sWl + FRAG(wot, whf, 1, wom)) = l1;
        }
        // stage P hi/lo: u32 gathers of pre-split x, perm-pack, b32 writes
        {
            int d0 = k0 + pair * 2;
            int c0 = d0 / 9, t0 = d0 - c0 * 9;
            int u0 = t0 / 3, v0 = t0 - u0 * 3;
            int t1 = t0 + 1, c1 = c0;
            if (t1 == 9) { t1 = 0; c1 = c0 + 1; }
            int u1 = t1 / 3, v1 = t1 - u1 * 3;
            int base0 = c0 * LPX + (u0 - 1) * WW + (v0 - 1);
            int base1 = c1 * LPX + (u1 - 1) * WW + (v1 - 1);
#pragma unroll
            for (int r = 0; r < 4; ++r) {
                int gy0 = ypx[r] + u0 - 1, gx0 = xpx[r] + v0 - 1;
                int gy1 = ypx[r] + u1 - 1, gx1 = xpx[r] + v1 - 1;
                int pxoff = ypx[r] * WW + xpx[r];
                unsigned g0 = ((unsigned)gy0 < HH && (unsigned)gx0 < WW)
                                  ? xb[base0 + pxoff] : 0u;
                unsigned g1 = ((unsigned)gy1 < HH && (unsigned)gx1 < WW)
                                  ? xb[base1 + pxoff] : 0u;
                unsigned hw = (g0 & 0xFFFFu) | (g1 << 16);          // h0|h1
                unsigned lw = (g0 >> 16) | (g1 & 0xFFFF0000u);      // l0|l1
                int pm = plane + (r & 1) * 16;
                int word = (r >> 1) * 512 + s_st * 256 + h_st * 128 + pm * 4 + j2_st;
                ((unsigned*)sPh)[word] = hw;
                ((unsigned*)sPl)[word] = lw;
            }
        }
        __syncthreads();
#pragma unroll
        for (int s = 0; s < 2; ++s) {
            short8 Ah[2], Al[2], Bh, Bl;
#pragma unroll
            for (int a = 0; a < 2; ++a) {
                int ot = aw * 2 + a;
                Ah[a] = *(const short8*)(sWh + FRAG(ot, s, half, lm));
                Al[a] = *(const short8*)(sWl + FRAG(ot, s, half, lm));
            }
            Bh = *(const short8*)(sPh + FRAG(nw, s, half, lm));
            Bl = *(const short8*)(sPl + FRAG(nw, s, half, lm));
#pragma unroll
            for (int a = 0; a < 2; ++a)
                acc[a] = __builtin_amdgcn_mfma_f32_32x32x16_bf16(Ah[a], Bh, acc[a], 0, 0, 0);
#pragma unroll
            for (int a = 0; a < 2; ++a)
                acc[a] = __builtin_amdgcn_mfma_f32_32x32x16_bf16(Ah[a], Bl, acc[a], 0, 0, 0);
#pragma unroll
            for (int a = 0; a < 2; ++a)
                acc[a] = __builtin_amdgcn_mfma_f32_32x32x16_bf16(Al[a], Bh, acc[a], 0, 0, 0);
        }
    }

    // epilogue: bias + parity decision + sentinel (D: row=o, col=px)
    const size_t outb = (size_t)b * COUT * LPX;
    const int pxg = pt0 + nw * 32 + lm;
#pragma unroll
    for (int a = 0; a < 2; ++a) {
        const int obase = aw * 64 + a * 32 + 4 * half;
#pragma unroll
        for (int reg = 0; reg < 16; ++reg) {
            int o = obase + (reg & 3) + 8 * (reg >> 2);
            float z = acc[a][reg] + bias[o];
            float q = rintf(__fmul_rn(z, 0.63661975f));
            float rr = fmaf(q, -1.5707964f, z);
            float d = fabsf(fabsf(rr) - 0.78539816f);
            out[outb + (size_t)o * LPX + pxg] =
                (d < MARGIN) ? SENT : (float)(((int)q) & 1);
        }
    }
}

// ---- MFMA conv B (R16 fallback, mid-size ws): 128o x 128px, on-the-fly split ----
__global__ __launch_bounds__(256, 3)
void conv_mfma_b(const float* __restrict__ x,
                 const unsigned short* __restrict__ Whg,
                 const unsigned short* __restrict__ Wlg,
                 const float* __restrict__ bias,
                 float* __restrict__ out) {
    __shared__ __align__(16) unsigned short sWh[4096];
    __shared__ __align__(16) unsigned short sWl[4096];
    __shared__ __align__(16) unsigned short sPh[4096];
    __shared__ __align__(16) unsigned short sPl[4096];
    const int tid = threadIdx.x;
    const int pt0 = blockIdx.x * 128;
    const int b   = blockIdx.y;
    const int plane = tid & 15, pair = tid >> 4;
    const int s_st = pair >> 3, h_st = (pair >> 2) & 1, j2_st = pair & 3;
    int ypx[8], xpx[8], vpx[8];
#pragma unroll
    for (int r = 0; r < 8; ++r) {
        int pxg = pt0 + plane + r * 16;
        ypx[r] = pxg / WW; xpx[r] = pxg - ypx[r] * WW; vpx[r] = (pxg < LPX);
    }
    const float* xb = x + (size_t)b * CIN * LPX;
    const int wo = tid >> 1, whf = tid & 1, wot = wo >> 5, wom = wo & 31;
    const int w = tid >> 6, lane = tid & 63, lm = lane & 31, half = lane >> 5;
    const int m0w = (w >> 1) * 64, n0w = (w & 1) * 64;
    float16v acc[2][2];
#pragma unroll
    for (int a = 0; a < 2; ++a)
#pragma unroll
        for (int n = 0; n < 2; ++n)
#pragma unroll
            for (int i = 0; i < 16; ++i) acc[a][n][i] = 0.f;
    for (int k0 = 0; k0 < DD; k0 += 32) {
        __syncthreads();
        {
            const uint4* sh = (const uint4*)(Whg + (size_t)wo * DD + k0 + whf * 16);
            const uint4* sl = (const uint4*)(Wlg + (size_t)wo * DD + k0 + whf * 16);
            uint4 h0 = sh[0], h1 = sh[1], l0 = sl[0], l1 = sl[1];
            *(uint4*)(sWh + FRAG(wot, whf, 0, wom)) = h0;
            *(uint4*)(sWh + FRAG(wot, whf, 1, wom)) = h1;
            *(uint4*)(sWl + FRAG(wot, whf, 0, wom)) = l0;
            *(uint4*)(sWl + FRAG(wot, whf, 1, wom)) = l1;
        }
        {
            int d0 = k0 + pair * 2;
            int c0 = d0 / 9, t0 = d0 - c0 * 9;
            int u0 = t0 / 3, v0 = t0 - u0 * 3;
            int t1 = t0 + 1, c1 = c0;
            if (t1 == 9) { t1 = 0; c1 = c0 + 1; }
            int u1 = t1 / 3, v1 = t1 - u1 * 3;
            int base0 = c0 * LPX + (u0 - 1) * WW + (v0 - 1);
            int base1 = c1 * LPX + (u1 - 1) * WW + (v1 - 1);
#pragma unroll
            for (int r = 0; r < 8; ++r) {
                int gy0 = ypx[r] + u0 - 1, gx0 = xpx[r] + v0 - 1;
                int gy1 = ypx[r] + u1 - 1, gx1 = xpx[r] + v1 - 1;
                int pxoff = ypx[r] * WW + xpx[r];
                float f0 = (vpx[r] && (unsigned)gy0 < HH && (unsigned)gx0 < WW) ? xb[base0 + pxoff] : 0.f;
                float f1 = (vpx[r] && (unsigned)gy1 < HH && (unsigned)gx1 < WW) ? xb[base1 + pxoff] : 0.f;
                unsigned short h0 = bf16_rne(f0), h1 = bf16_rne(f1);
                unsigned short l0 = bf16_rne(f0 - bf16_to_f(h0)), l1 = bf16_rne(f1 - bf16_to_f(h1));
                int pm = plane + (r & 1) * 16;
                int word = ((r >> 1) * 512 + s_st * 256 + h_st * 128 + pm * 4 + j2_st);
                ((unsigned*)sPh)[word] = (unsigned)h0 | ((unsigned)h1 << 16);
                ((unsigned*)sPl)[word] = (unsigned)l0 | ((unsigned)l1 << 16);
            }
        }
        __syncthreads();
#pragma unroll
        for (int s = 0; s < 2; ++s) {
            short8 Ah[2], Al[2], Bh[2], Bl[2];
#pragma unroll
            for (int a = 0; a < 2; ++a) {
                int ot = (w >> 1) * 2 + a;
                Ah[a] = *(const short8*)(sWh + FRAG(ot, s, half, lm));
                Al[a] = *(const short8*)(sWl + FRAG(ot, s, half, lm));
            }
#pragma unroll
            for (int n = 0; n < 2; ++n) {
                int pt = (w & 1) * 2 + n;
                Bh[n] = *(const short8*)(sPh + FRAG(pt, s, half, lm));
                Bl[n] = *(const short8*)(sPl + FRAG(pt, s, half, lm));
            }
#pragma unroll
            for (int a = 0; a < 2; ++a)
#pragma unroll
                for (int n = 0; n < 2; ++n)
                    acc[a][n] = __builtin_amdgcn_mfma_f32_32x32x16_bf16(Ah[a], Bh[n], acc[a][n], 0, 0, 0);
#pragma unroll
            for (int a = 0; a < 2; ++a)
#pragma unroll
                for (int n = 0; n < 2; ++n)
                    acc[a][n] = __builtin_amdgcn_mfma_f32_32x32x16_bf16(Ah[a], Bl[n], acc[a][n], 0, 0, 0);
#pragma unroll
            for (int a = 0; a < 2; ++a)
#pragma unroll
                for (int n = 0; n < 2; ++n)
                    acc[a][n] = __builtin_amdgcn_mfma_f32_32x32x16_bf16(Al[a], Bh[n], acc[a][n], 0, 0, 0);
        }
    }
    const size_t outb = (size_t)b * COUT * LPX;
#pragma unroll
    for (int a = 0; a < 2; ++a) {
        const int obase = m0w + a * 32 + 4 * half;
#pragma unroll
        for (int n = 0; n < 2; ++n) {
            if (pt0 + n0w + n * 32 >= LPX) continue;
            const int pxg = pt0 + n0w + n * 32 + lm;
#pragma unroll
            for (int reg = 0; reg < 16; ++reg) {
                int o = obase + (reg & 3) + 8 * (reg >> 2);
                float z = acc[a][n][reg] + bias[o];
                float q = rintf(__fmul_rn(z, 0.63661975f));
                float rr = fmaf(q, -1.5707964f, z);
                float d = fabsf(fabsf(rr) - 0.78539816f);
                out[outb + (size_t)o * LPX + pxg] = (d < MARGIN) ? SENT : (float)(((int)q) & 1);
            }
        }
    }
}

// ---- sentinel scan (float4) + bit-exact replay of verified R9 path ----
__global__ __launch_bounds__(256)
void exact_fix(const float* __restrict__ x,
               const float* __restrict__ Wt,
               const float* __restrict__ bias,
               float* __restrict__ out) {
#pragma clang fp contract(off)
    int q4 = blockIdx.x * 256 + threadIdx.x;
    if (q4 * 4 >= TOTAL) return;
    float4 v = *(const float4*)(out + (size_t)q4 * 4);
    float vv[4] = {v.x, v.y, v.z, v.w};
#pragma unroll
    for (int e = 0; e < 4; ++e) {
        if (vv[e] != SENT) continue;
        int idx = q4 * 4 + e;
        int px = idx % WW;
        unsigned t = idx / WW;
        int py = t % HH;  t /= HH;
        int o  = t % COUT;
        int b  = t / COUT;
        const float* wrow = Wt + (size_t)o * DD;
        const float* xb   = x + (size_t)b * CIN * LPX;
        int  voff[9];
        bool vok[9];
#pragma unroll
        for (int u = 0; u < 3; ++u)
#pragma unroll
            for (int vv2 = 0; vv2 < 3; ++vv2) {
                int gy = py + u - 1, gx = px + vv2 - 1;
                vok[u * 3 + vv2]  = ((unsigned)gy < HH) && ((unsigned)gx < WW);
                voff[u * 3 + vv2] = gy * WW + gx;
            }
        float accA = 0.f, accB2 = 0.f;
        for (int c = 0; c < CIN; ++c) {
            const float* xc = xb + c * LPX;
            const float* wc = wrow + c * 9;
            int dbase = c * 9;
#pragma unroll
            for (int tp = 0; tp < 9; ++tp) {
                float p = vok[tp] ? xc[voff[tp]] : 0.f;
                float wv = wc[tp];
                if (dbase + tp < KC) accA  = fmaf(p, wv, accA);
                else                 accB2 = fmaf(p, wv, accB2);
            }
        }
        float zG = __fadd_rn(accA, accB2);
        float z  = __fadd_rn(zG, bias[o]);
        out[idx] = (float)dec_np(z);
    }
}

// ---- fallback (verified R9 path) ----
__global__ __launch_bounds__(256)
void np_emul_conv(const float* __restrict__ x,
                  const float* __restrict__ Wt,
                  const float* __restrict__ bias,
                  float* __restrict__ out) {
#pragma clang fp contract(off)
    int idx = blockIdx.x * 256 + threadIdx.x;
    if (idx >= TOTAL) return;
    int px = idx % WW;
    int t  = idx / WW;
    int py = t % HH;  t /= HH;
    int o  = t % COUT;
    int b  = t / COUT;
    const float* wrow = Wt + (size_t)o * DD;
    const float* xb   = x + (size_t)b * CIN * LPX;
    float accA = 0.f, accB2 = 0.f;
    for (int c = 0; c < CIN; ++c) {
        const float* xc = xb + c * LPX;
        const float* wc = wrow + c * 9;
        int dbase = c * 9;
#pragma unroll
        for (int u = 0; u < 3; ++u)
#pragma unroll
            for (int v = 0; v < 3; ++v) {
                int tp = u * 3 + v;
                int gy = py + u - 1, gx = px + v - 1;
                float p = ((unsigned)gy < HH && (unsigned)gx < WW) ? xc[gy * WW + gx] : 0.f;
                if (dbase + tp < KC) accA  = fmaf(p, wc[tp], accA);
                else                 accB2 = fmaf(p, wc[tp], accB2);
            }
    }
    float z = __fadd_rn(__fadd_rn(accA, accB2), bias[o]);
    out[idx] = (float)dec_np(z);
}

extern "C" void kernel_launch(void* const* d_in, const int* in_sizes, int n_in,
                              void* d_out, int out_size, void* d_ws, size_t ws_size,
                              hipStream_t stream) {
    const float* x  = (const float*)d_in[0];
    const float* Wt = (const float*)d_in[1];
    const float* bb = (const float*)d_in[2];
    float* out = (float*)d_out;

    const size_t WSPLIT = (size_t)COUT * DD * 2;          // 147456 B each
    const size_t XS     = (size_t)NX * 4;                 // 25.7 MB
    unsigned short* Whg = (unsigned short*)d_ws;
    unsigned short* Wlg = Whg + COUT * DD;

    if (ws_size >= 2 * WSPLIT + XS) {                     // tier A: pre-split x
        unsigned* xsv = (unsigned*)((char*)d_ws + 2 * WSPLIT);
        prep_w<<<dim3((COUT * DD + 255) / 256), dim3(256), 0, stream>>>(Wt, Whg, Wlg);
        prep_x<<<dim3((NX + 255) / 256), dim3(256), 0, stream>>>(x, xsv);
        conv_mfma<<<dim3(49, B_), dim3(256), 0, stream>>>(xsv, Whg, Wlg, bb, out);
        exact_fix<<<dim3((TOTAL / 4 + 255) / 256), dim3(256), 0, stream>>>(x, Wt, bb, out);
    } else if (ws_size >= 2 * WSPLIT) {                   // tier B: R16 path
        prep_w<<<dim3((COUT * DD + 255) / 256), dim3(256), 0, stream>>>(Wt, Whg, Wlg);
        conv_mfma_b<<<dim3(25, B_), dim3(256), 0, stream>>>(x, Whg, Wlg, bb, out);
        exact_fix<<<dim3((TOTAL / 4 + 255) / 256), dim3(256), 0, stream>>>(x, Wt, bb, out);
    } else {                                              // tier C: verified naive
        np_emul_conv<<<(TOTAL + 255) / 256, 256, 0, stream>>>(x, Wt, bb, out);
    }
}